// Round 2
// baseline (3095.819 us; speedup 1.0000x reference)
//
#include <hip/hip_runtime.h>
#include <math.h>

#define H 256
#define R 4  // rows per block

__global__ __launch_bounds__(256) void fte_kernel(
    const float* __restrict__ x,
    const float* __restrict__ vec,
    const float* __restrict__ W_equi,
    const float* __restrict__ W1,
    const float* __restrict__ b1,
    const float* __restrict__ W2,
    const float* __restrict__ b2,
    float* __restrict__ dx,
    float* __restrict__ dvec,
    int N)
{
    __shared__ float vec_s[3 * R * H];   // GEMM1 A operand, m = r*3+c
    __shared__ float v1_s[3 * R * H];    // v[..., :H]
    __shared__ float v2_s[3 * R * H];    // v[..., H:]
    __shared__ float hin_s[R * 2 * H];   // concat(x, scalar)
    __shared__ float h_s[R * H];         // silu output

    const int t = threadIdx.x;
    const int row0 = blockIdx.x * R;

    // ---- stage vec -> LDS, zero-pad partial tiles ----
    {
        const int valid = (N - row0) < R ? (N - row0) : R;
        const int total = valid * 3 * H;
        const float* src = vec + (size_t)row0 * 3 * H;
        if (total == 3 * R * H) {
            // full tile: float4 copy (768 float4s, 3 per thread)
            const float4* s4 = (const float4*)src;
            float4* d4 = (float4*)vec_s;
            #pragma unroll
            for (int i = 0; i < 3; ++i) d4[t + 256 * i] = s4[t + 256 * i];
        } else {
            for (int i = t; i < total; i += 256) vec_s[i] = src[i];
            for (int i = total + t; i < 3 * R * H; i += 256) vec_s[i] = 0.f;
        }
    }
    __syncthreads();

    // ---- GEMM1: (3R x H) @ W_equi (H x 2H); thread t owns cols 2t, 2t+1 ----
    float acc0[3 * R], acc1[3 * R];
    #pragma unroll
    for (int m = 0; m < 3 * R; ++m) { acc0[m] = 0.f; acc1[m] = 0.f; }
    for (int h = 0; h < H; h += 4) {
        float w0[4], w1[4];
        #pragma unroll
        for (int u = 0; u < 4; ++u) {
            const float2 w = *(const float2*)&W_equi[(size_t)(h + u) * 2 * H + 2 * t];
            w0[u] = w.x;
            w1[u] = w.y;
        }
        #pragma unroll
        for (int m = 0; m < 3 * R; ++m) {
            const float4 a = *(const float4*)&vec_s[m * H + h];
            acc0[m] += a.x * w0[0]; acc1[m] += a.x * w1[0];
            acc0[m] += a.y * w0[1]; acc1[m] += a.y * w1[1];
            acc0[m] += a.z * w0[2]; acc1[m] += a.z * w1[2];
            acc0[m] += a.w * w0[3]; acc1[m] += a.w * w1[3];
        }
    }
    {
        // cols 2t,2t+1: t<128 -> vec1 (cols 0..255), t>=128 -> vec2 (cols 256..511)
        float* dst = (t < 128) ? v1_s : v2_s;
        const int kk = (2 * t) & (H - 1);
        #pragma unroll
        for (int m = 0; m < 3 * R; ++m) {
            float2 p; p.x = acc0[m]; p.y = acc1[m];
            *(float2*)&dst[m * H + kk] = p;
        }
    }
    __syncthreads();

    // ---- reductions: scalar = ||v1||_c, vec_dot = <v1,v2>_c / sqrt(H) ----
    float vd[R];
    #pragma unroll
    for (int r = 0; r < R; ++r) {
        float s = 0.f, d = 0.f;
        #pragma unroll
        for (int c = 0; c < 3; ++c) {
            const float a = v1_s[(r * 3 + c) * H + t];
            const float b = v2_s[(r * 3 + c) * H + t];
            s += a * a;
            d += a * b;
        }
        vd[r] = d * (1.0f / 16.0f);  // 1/sqrt(256)
        hin_s[r * 2 * H + H + t] = sqrtf(s);
        float xv = 0.f;
        if (row0 + r < N) xv = x[(size_t)(row0 + r) * H + t];
        hin_s[r * 2 * H + t] = xv;
    }
    __syncthreads();

    // ---- GEMM2: (R x 2H) @ W1 (2H x H) + b1, silu; thread t owns col t ----
    float acc2[R];
    #pragma unroll
    for (int r = 0; r < R; ++r) acc2[r] = 0.f;
    for (int k = 0; k < 2 * H; k += 4) {
        float w[4];
        #pragma unroll
        for (int u = 0; u < 4; ++u) w[u] = W1[(size_t)(k + u) * H + t];
        #pragma unroll
        for (int r = 0; r < R; ++r) {
            const float4 a = *(const float4*)&hin_s[r * 2 * H + k];
            acc2[r] += a.x * w[0];
            acc2[r] += a.y * w[1];
            acc2[r] += a.z * w[2];
            acc2[r] += a.w * w[3];
        }
    }
    {
        const float bv = b1[t];
        #pragma unroll
        for (int r = 0; r < R; ++r) {
            const float z = acc2[r] + bv;
            h_s[r * H + t] = z / (1.f + __expf(-z));  // silu
        }
    }
    __syncthreads();

    // ---- GEMM3: (R x H) @ W2 (H x 3H); thread t owns cols t, t+H, t+2H ----
    float a3[R][3];
    #pragma unroll
    for (int r = 0; r < R; ++r)
        #pragma unroll
        for (int c = 0; c < 3; ++c) a3[r][c] = 0.f;
    for (int k = 0; k < H; k += 4) {
        float wc[4][3];
        #pragma unroll
        for (int u = 0; u < 4; ++u) {
            const float* wr = W2 + (size_t)(k + u) * 3 * H + t;
            wc[u][0] = wr[0];
            wc[u][1] = wr[H];
            wc[u][2] = wr[2 * H];
        }
        #pragma unroll
        for (int r = 0; r < R; ++r) {
            const float4 a = *(const float4*)&h_s[r * H + k];
            #pragma unroll
            for (int c = 0; c < 3; ++c) {
                a3[r][c] += a.x * wc[0][c];
                a3[r][c] += a.y * wc[1][c];
                a3[r][c] += a.z * wc[2][c];
                a3[r][c] += a.w * wc[3][c];
            }
        }
    }

    // ---- epilogue ----
    const float bv0 = b2[t];
    const float bv1 = b2[H + t];
    const float bv2 = b2[2 * H + t];
    const float inv_sqrt2 = 0.70710678118654752440f;
    #pragma unroll
    for (int r = 0; r < R; ++r) {
        const int n = row0 + r;
        if (n >= N) break;
        const float xv1 = a3[r][0] + bv0;
        const float xv2 = a3[r][1] + bv1;
        const float xv3 = a3[r][2] + bv2;
        dx[(size_t)n * H + t] = (xv1 + xv2 + vd[r]) * inv_sqrt2;
        #pragma unroll
        for (int c = 0; c < 3; ++c) {
            dvec[(size_t)n * 3 * H + c * H + t] = xv3 * v2_s[(r * 3 + c) * H + t];
        }
    }
}

extern "C" void kernel_launch(void* const* d_in, const int* in_sizes, int n_in,
                              void* d_out, int out_size, void* d_ws, size_t ws_size,
                              hipStream_t stream) {
    const float* x      = (const float*)d_in[0];
    const float* vec    = (const float*)d_in[1];
    // d_in[2] = node_frame: unused by the reference computation
    const float* W_equi = (const float*)d_in[3];
    const float* W1     = (const float*)d_in[4];
    const float* b1     = (const float*)d_in[5];
    const float* W2     = (const float*)d_in[6];
    const float* b2     = (const float*)d_in[7];

    const int N = in_sizes[0] / H;
    float* dx   = (float*)d_out;
    float* dvec = (float*)d_out + (size_t)N * H;

    const int blocks = (N + R - 1) / R;
    fte_kernel<<<blocks, 256, 0, stream>>>(x, vec, W_equi, W1, b1, W2, b2, dx, dvec, N);
}